// Round 11
// baseline (137.227 us; speedup 1.0000x reference)
//
#include <hip/hip_runtime.h>

// Medical2DSliceRenderer on MI355X (gfx950) — round 11
//
//   mm = c0 x^2 + c1 xy + c2 y^2 + c3 x + c4 y + c5'
//   with c5' = quad(mu) + log2(op*mask) + L,  L = 0.5*log2(ftop), r = 2^-L
//   h = exp2(mm);  S1 += h*r (= g*op);  S2 += h*h (= g^2*op*ft)
//   img = sum_c [prod_{c'<c}(1-S1_c')] * S2_c
//
// Round 11: replace the s_load feed (whose lgkmcnt drains stalled ~28% and
// were occupancy-invariant -> correlated) with a VMEM feed: per batch of 64
// gaussians, lane l loads gaussian l's 8 coeffs via two coalesced dwordx4
// (split A/B planes), then the g-loop broadcasts coeffs to SGPRs with
// v_readlane_b32 (8/gaussian, 0.03 cy/elem amortized). VMEM is deeply
// pipelined (vmcnt-counted) so the feed latency hides under ~9600cy of
// compute. rsqrt-fold removes the g*g mul: core = 5 VALU + 1 exp2 / elem,
// all row-ops <=1 SGPR operand (no v_mov padding).

#define EPSV 1e-6f
#define NG   4096
#define PP   16384
#define NSL  4
#define NCS  32          // (chunk,seg) units: 4 chunks x 8 segments
#define GSEG 128         // gaussians per segment (2 batches of 64)

#define RL(v, g) __int_as_float(__builtin_amdgcn_readlane(__float_as_int(v), (g)))

__global__ void prep_kernel(const float* __restrict__ means,
                            const float* __restrict__ scales,
                            const float* __restrict__ rots,
                            const float* __restrict__ ops,
                            const float* __restrict__ fts,
                            float4* __restrict__ gA,
                            float4* __restrict__ gB) {
    __shared__ float red[256];
    int tid = threadIdx.x;

    float m = -1e30f;
    for (int i = tid; i < NG; i += 256) m = fmaxf(m, scales[i*3+2]);
    red[tid] = m;
    __syncthreads();
    for (int s = 128; s > 0; s >>= 1) {
        if (tid < s) red[tid] = fmaxf(red[tid], red[tid+s]);
        __syncthreads();
    }
    float maxd = 3.0f * red[0];

    int g = blockIdx.x * 256 + tid;
    if (g >= NG) return;

    float qw = rots[g*4+0], qx = rots[g*4+1], qy = rots[g*4+2], qz = rots[g*4+3];
    float inorm = rsqrtf(qw*qw + qx*qx + qy*qy + qz*qz);
    qw *= inorm; qx *= inorm; qy *= inorm; qz *= inorm;

    float s0 = scales[g*3+0], s1 = scales[g*3+1], s2 = scales[g*3+2];

    float r00 = 1.f - 2.f*(qy*qy + qz*qz), r01 = 2.f*(qx*qy - qw*qz), r02 = 2.f*(qx*qz + qw*qy);
    float r10 = 2.f*(qx*qy + qw*qz), r11 = 1.f - 2.f*(qx*qx + qz*qz), r12 = 2.f*(qy*qz - qw*qx);
    float r20 = 2.f*(qx*qz - qw*qy), r21 = 2.f*(qy*qz + qw*qx), r22 = 1.f - 2.f*(qx*qx + qy*qy);

    float a00 = r00*s0, a01 = r01*s1, a02 = r02*s2;
    float a10 = r10*s0, a11 = r11*s1, a12 = r12*s2;
    float a20 = r20*s0, a21 = r21*s1, a22 = r22*s2;

    float c00 = a00*a00 + a01*a01 + a02*a02;
    float c01 = a00*a10 + a01*a11 + a02*a12;
    float c02 = a00*a20 + a01*a21 + a02*a22;
    float c11 = a10*a10 + a11*a11 + a12*a12;
    float c12 = a10*a20 + a11*a21 + a12*a22;
    float c22 = a20*a20 + a21*a21 + a22*a22;

    float izz = 1.0f / (c22 + EPSV);
    float kx = c02 * izz, ky = c12 * izz;
    float sa = c00 - c02*c02*izz + EPSV;
    float sb = c01 - c02*c12*izz;
    float sd = c11 - c12*c12*izz + EPSV;
    float det = sa*sd - sb*sb;
    float idet = 1.0f / det;

    const float C0 = -0.72134752044448170f;   // -0.5 * log2(e)
    float qa = C0 * sd * idet;            // x^2 coeff
    float qb = C0 * (-2.0f * sb * idet);  // xy coeff
    float qd = C0 * sa * idet;            // y^2 coeff

    float mx = means[g*3+0], my = means[g*3+1], mz = means[g*3+2];
    float op = ops[g], ft = fts[g];

    #pragma unroll
    for (int s = 0; s < NSL; ++s) {
        float z = -0.15f + 0.1f * (float)s;
        float zoff = z - mz;
        float m2x = mx + kx * zoff;
        float m2y = my + ky * zoff;
        bool live = (fabsf(mz - z) < maxd) && (op > 1e-12f);

        float c3 = -(2.0f*qa*m2x + qb*m2y);
        float c4 = -(2.0f*qd*m2y + qb*m2x);
        float c5q = qa*m2x*m2x + qb*m2x*m2y + qd*m2y*m2y;

        float c5p, rr;
        if (live) {
            float lop  = __log2f(op);
            float ftop = fmaxf(ft / op, 1e-20f);
            float L    = 0.5f * __log2f(ftop);
            c5p = c5q + lop + L;
            rr  = exp2f(-L);
        } else {
            c5p = -__builtin_inff();
            rr  = 0.f;
        }
        size_t o = (size_t)s * NG + g;
        gA[o] = make_float4(qa, qb, qd, c3);
        gB[o] = make_float4(c4, c5p, rr, 0.f);
    }
}

// 1024 blocks x 256 thr (4 waves). b: cs = b&31 (chunk*8+seg), band = b>>5
// (slice, 16-row band). Wave w: ch = w&1 column half, (w>>1) = 8-row group.
// Segment = 128 gaussians, fed as 2 batches of 64 via per-lane VMEM loads.
__global__ __launch_bounds__(256, 6)
void render_kernel(const float4* __restrict__ gA,
                   const float4* __restrict__ gB,
                   float2* __restrict__ part) {
    int tid   = threadIdx.x;
    int lane  = tid & 63;
    int w     = __builtin_amdgcn_readfirstlane(tid >> 6);   // 0..3
    int b     = blockIdx.x;
    int cs    = b & (NCS - 1);
    int band  = b >> 5;
    int slice = band >> 3;
    int ch    = w & 1;
    int rbase = (band & 7) * 16 + (w >> 1) * 8;

    const float DL = 2.0f / 127.0f;
    float x = -1.0f + (float)(ch * 64 + lane) * DL;   // per-lane column

    float yv[8];
    #pragma unroll
    for (int j = 0; j < 8; ++j) yv[j] = -1.0f + (float)(rbase + j) * DL;

    float s1[8], s2[8];
    #pragma unroll
    for (int j = 0; j < 8; ++j) { s1[j] = 0.f; s2[j] = 0.f; }

    size_t segoff = (size_t)slice * NG + (size_t)cs * GSEG;
    // issue all 4 feed loads up-front (VMEM, vmcnt-pipelined)
    float4 vA0 = gA[segoff + lane];
    float4 vB0 = gB[segoff + lane];
    float4 vA1 = gA[segoff + 64 + lane];
    float4 vB1 = gB[segoff + 64 + lane];

    #pragma unroll 1
    for (int batch = 0; batch < 2; ++batch) {
        float4 vA = batch ? vA1 : vA0;
        float4 vB = batch ? vB1 : vB0;
        #pragma unroll 8
        for (int g = 0; g < 64; ++g) {
            float c0 = RL(vA.x, g), c1 = RL(vA.y, g);
            float c2 = RL(vA.z, g), c3 = RL(vA.w, g);
            float c4 = RL(vB.x, g), c5 = RL(vB.y, g);
            float rr = RL(vB.z, g);
            float A1 = fmaf(c0, x, c3);
            float A2 = fmaf(c1, x, c4);
            float A3 = fmaf(A1, x, c5);
            #pragma unroll
            for (int j = 0; j < 8; ++j) {
                float wj = fmaf(c2, yv[j], A2);
                float mj = fmaf(wj, yv[j], A3);
                float h  = __builtin_amdgcn_exp2f(mj);
                s1[j] = fmaf(h, rr, s1[j]);   // h * 2^-L = g*op
                s2[j] = fmaf(h, h,  s2[j]);   // h^2 = g^2*op*ft
            }
        }
    }

    // plane-major partials: part[cs][slice*PP + row*128 + col]  (coalesced)
    size_t ob = (size_t)cs * (NSL * PP) + (size_t)slice * PP
              + (size_t)rbase * 128 + ch * 64 + lane;
    #pragma unroll
    for (int j = 0; j < 8; ++j)
        part[ob + (size_t)j * 128] = make_float2(s1[j], s2[j]);
}

// one thread per pixel: sum 8 segments per chunk, then 4-step recursion
__global__ __launch_bounds__(256)
void combine_kernel(const float2* __restrict__ part, float* __restrict__ out) {
    int px = blockIdx.x * 256 + threadIdx.x;
    float img = 0.f, acc = 0.f;
    #pragma unroll
    for (int c = 0; c < 4; ++c) {
        float S1 = 0.f, S2 = 0.f;
        #pragma unroll
        for (int s = 0; s < 8; ++s) {
            float2 v = part[(size_t)(c*8 + s) * (NSL*PP) + px];
            S1 += v.x;  S2 += v.y;
        }
        float om = 1.0f - acc;
        img = fmaf(om, S2, img);
        acc = fmaf(om, S1, acc);
    }
    out[px] = img;
}

extern "C" void kernel_launch(void* const* d_in, const int* in_sizes, int n_in,
                              void* d_out, int out_size, void* d_ws, size_t ws_size,
                              hipStream_t stream) {
    const float* means  = (const float*)d_in[0];
    const float* scales = (const float*)d_in[1];
    const float* rots   = (const float*)d_in[2];
    const float* ops    = (const float*)d_in[3];
    const float* fts    = (const float*)d_in[4];
    float* out = (float*)d_out;

    float4* gA   = (float4*)d_ws;                                  // 256 KB
    float4* gB   = (float4*)((char*)d_ws + (size_t)NSL*NG*16);     // 256 KB
    float2* part = (float2*)((char*)d_ws + (size_t)NSL*NG*32);     // 16.8 MB

    prep_kernel<<<NG/256, 256, 0, stream>>>(means, scales, rots, ops, fts, gA, gB);
    render_kernel<<<NCS * 32, 256, 0, stream>>>(gA, gB, part);
    combine_kernel<<<NSL*PP/256, 256, 0, stream>>>(part, out);
}

// Round 12
// 128.291 us; speedup vs baseline: 1.0696x; 1.0696x over previous
//
#include <hip/hip_runtime.h>

// Medical2DSliceRenderer on MI355X (gfx950) — round 12
//
//   mm = c0 x^2 + c1 xy + c2 y^2 + c3 x + c4 y + c5'
//   c5' = quad(mu) + log2(op*mask) + L,  L = 0.5*log2(ft/op), rr = 2^-L
//   h = exp2(mm);  S1 += h*rr (= g*op);  S2 += h*h (= g^2*op*ft)
//   img = sum_c [prod_{c'<c}(1-S1_c')] * S2_c
//
// Round 12: LDS-broadcast feed. History: s_load feed stalls ~28% on
// out-of-order SMEM -> full lgkmcnt(0) drains per unroll group (R9/R10:
// occupancy-invariant); readlane feed pays 8 VALU/g + SGPR hazards (R11
// regressed). DS reads return IN-ORDER -> compiler emits partial
// lgkmcnt(N) waits and pipelines across groups; same-address wave reads
// broadcast conflict-free; coeffs land in VGPRs (no SGPR-operand limits).
// LDS traffic amortized over 8 rows/lane: ~61 B/cy/CU << 128 peak (R1's
// mistake was per-pixel ds_reads). Core: 4 VALU + 1 exp2 per elem.

#define EPSV 1e-6f
#define NG   4096
#define PP   16384
#define NSL  4
#define NCS  32          // (chunk,seg) units: 4 chunks x 8 segments
#define GSEG 128         // gaussians per segment

__global__ void prep_kernel(const float* __restrict__ means,
                            const float* __restrict__ scales,
                            const float* __restrict__ rots,
                            const float* __restrict__ ops,
                            const float* __restrict__ fts,
                            float4* __restrict__ gdata) {
    __shared__ float red[256];
    int tid = threadIdx.x;

    float m = -1e30f;
    for (int i = tid; i < NG; i += 256) m = fmaxf(m, scales[i*3+2]);
    red[tid] = m;
    __syncthreads();
    for (int s = 128; s > 0; s >>= 1) {
        if (tid < s) red[tid] = fmaxf(red[tid], red[tid+s]);
        __syncthreads();
    }
    float maxd = 3.0f * red[0];

    int g = blockIdx.x * 256 + tid;
    if (g >= NG) return;

    float qw = rots[g*4+0], qx = rots[g*4+1], qy = rots[g*4+2], qz = rots[g*4+3];
    float inorm = rsqrtf(qw*qw + qx*qx + qy*qy + qz*qz);
    qw *= inorm; qx *= inorm; qy *= inorm; qz *= inorm;

    float s0 = scales[g*3+0], s1 = scales[g*3+1], s2 = scales[g*3+2];

    float r00 = 1.f - 2.f*(qy*qy + qz*qz), r01 = 2.f*(qx*qy - qw*qz), r02 = 2.f*(qx*qz + qw*qy);
    float r10 = 2.f*(qx*qy + qw*qz), r11 = 1.f - 2.f*(qx*qx + qz*qz), r12 = 2.f*(qy*qz - qw*qx);
    float r20 = 2.f*(qx*qz - qw*qy), r21 = 2.f*(qy*qz + qw*qx), r22 = 1.f - 2.f*(qx*qx + qy*qy);

    float a00 = r00*s0, a01 = r01*s1, a02 = r02*s2;
    float a10 = r10*s0, a11 = r11*s1, a12 = r12*s2;
    float a20 = r20*s0, a21 = r21*s1, a22 = r22*s2;

    float c00 = a00*a00 + a01*a01 + a02*a02;
    float c01 = a00*a10 + a01*a11 + a02*a12;
    float c02 = a00*a20 + a01*a21 + a02*a22;
    float c11 = a10*a10 + a11*a11 + a12*a12;
    float c12 = a10*a20 + a11*a21 + a12*a22;
    float c22 = a20*a20 + a21*a21 + a22*a22;

    float izz = 1.0f / (c22 + EPSV);
    float kx = c02 * izz, ky = c12 * izz;
    float sa = c00 - c02*c02*izz + EPSV;
    float sb = c01 - c02*c12*izz;
    float sd = c11 - c12*c12*izz + EPSV;
    float det = sa*sd - sb*sb;
    float idet = 1.0f / det;

    const float C0 = -0.72134752044448170f;   // -0.5 * log2(e)
    float qa = C0 * sd * idet;            // x^2 coeff
    float qb = C0 * (-2.0f * sb * idet);  // xy coeff
    float qd = C0 * sa * idet;            // y^2 coeff

    float mx = means[g*3+0], my = means[g*3+1], mz = means[g*3+2];
    float op = ops[g], ft = fts[g];

    #pragma unroll
    for (int s = 0; s < NSL; ++s) {
        float z = -0.15f + 0.1f * (float)s;
        float zoff = z - mz;
        float m2x = mx + kx * zoff;
        float m2y = my + ky * zoff;
        bool live = (fabsf(mz - z) < maxd) && (op > 1e-12f);

        float c3 = -(2.0f*qa*m2x + qb*m2y);
        float c4 = -(2.0f*qd*m2y + qb*m2x);
        float c5q = qa*m2x*m2x + qb*m2x*m2y + qd*m2y*m2y;

        float c5p, rr;
        if (live) {
            float lop  = __log2f(op);
            float ftop = fmaxf(ft / op, 1e-20f);
            float L    = 0.5f * __log2f(ftop);
            c5p = c5q + lop + L;
            rr  = exp2f(-L);
        } else {
            c5p = -__builtin_inff();
            rr  = 0.f;
        }
        float4* o = gdata + ((size_t)s * NG + g) * 2;
        o[0] = make_float4(qa, qb, qd, c3);    // c0 c1 c2 c3
        o[1] = make_float4(c4, c5p, rr, 0.f);  // c4 c5' rr pad
    }
}

// 1024 blocks x 256 thr (4 waves). b: cs = b&31 (chunk*8+seg), band = b>>5.
// Wave w: ch = w&1 column half, w>>1 = 8-row group (block = 16 rows x 128).
// Segment (128 g, 4KB) staged to LDS once; inner loop: 2 broadcast
// ds_read_b128 per gaussian per wave, amortized over 512 px.
__global__ __launch_bounds__(256, 4)
void render_kernel(const float4* __restrict__ gdata, float2* __restrict__ part) {
    __shared__ float4 sg[GSEG * 2];   // 4 KB

    int tid   = threadIdx.x;
    int lane  = tid & 63;
    int w     = __builtin_amdgcn_readfirstlane(tid >> 6);   // 0..3
    int b     = blockIdx.x;
    int cs    = b & (NCS - 1);
    int band  = b >> 5;          // 0..31
    int slice = band >> 3;
    int ch    = w & 1;
    int rbase = (band & 7) * 16 + (w >> 1) * 8;

    // stage segment: 256 threads x 1 float4
    sg[tid] = gdata[((size_t)slice * NG + (size_t)cs * GSEG) * 2 + tid];
    __syncthreads();

    const float DL = 2.0f / 127.0f;
    float x = -1.0f + (float)(ch * 64 + lane) * DL;   // per-lane column

    float yv[8];
    #pragma unroll
    for (int j = 0; j < 8; ++j) yv[j] = -1.0f + (float)(rbase + j) * DL;

    float s1[8], s2[8];
    #pragma unroll
    for (int j = 0; j < 8; ++j) { s1[j] = 0.f; s2[j] = 0.f; }

    #pragma unroll 4
    for (int g = 0; g < GSEG; ++g) {
        float4 A = sg[2*g+0];   // c0 c1 c2 c3   (broadcast ds_read_b128)
        float4 B = sg[2*g+1];   // c4 c5' rr pad
        float A1 = fmaf(A.x, x, A.w);    // c0*x + c3
        float A2 = fmaf(A.y, x, B.x);    // c1*x + c4
        float A3 = fmaf(A1,  x, B.y);    // A1*x + c5'
        float rr = B.z;
        #pragma unroll
        for (int j = 0; j < 8; ++j) {
            float wj = fmaf(A.z, yv[j], A2);
            float mj = fmaf(wj, yv[j], A3);
            float h  = __builtin_amdgcn_exp2f(mj);
            s1[j] = fmaf(h, rr, s1[j]);   // = g*op
            s2[j] = fmaf(h, h,  s2[j]);   // = g^2*op*ft
        }
    }

    // plane-major partials: part[cs][slice*PP + row*128 + col]  (coalesced)
    size_t ob = (size_t)cs * (NSL * PP) + (size_t)slice * PP
              + (size_t)rbase * 128 + ch * 64 + lane;
    #pragma unroll
    for (int j = 0; j < 8; ++j)
        part[ob + (size_t)j * 128] = make_float2(s1[j], s2[j]);
}

// one thread per pixel: sum 8 segments per chunk, then 4-step recursion
__global__ __launch_bounds__(256)
void combine_kernel(const float2* __restrict__ part, float* __restrict__ out) {
    int px = blockIdx.x * 256 + threadIdx.x;
    float img = 0.f, acc = 0.f;
    #pragma unroll
    for (int c = 0; c < 4; ++c) {
        float S1 = 0.f, S2 = 0.f;
        #pragma unroll
        for (int s = 0; s < 8; ++s) {
            float2 v = part[(size_t)(c*8 + s) * (NSL*PP) + px];
            S1 += v.x;  S2 += v.y;
        }
        float om = 1.0f - acc;
        img = fmaf(om, S2, img);
        acc = fmaf(om, S1, acc);
    }
    out[px] = img;
}

extern "C" void kernel_launch(void* const* d_in, const int* in_sizes, int n_in,
                              void* d_out, int out_size, void* d_ws, size_t ws_size,
                              hipStream_t stream) {
    const float* means  = (const float*)d_in[0];
    const float* scales = (const float*)d_in[1];
    const float* rots   = (const float*)d_in[2];
    const float* ops    = (const float*)d_in[3];
    const float* fts    = (const float*)d_in[4];
    float* out = (float*)d_out;

    float4* gdata = (float4*)d_ws;                               // 512 KB
    float2* part  = (float2*)((char*)d_ws + (size_t)NSL*NG*32);  // 16.8 MB

    prep_kernel<<<NG/256, 256, 0, stream>>>(means, scales, rots, ops, fts, gdata);
    render_kernel<<<NCS * 32, 256, 0, stream>>>(gdata, part);
    combine_kernel<<<NSL*PP/256, 256, 0, stream>>>(part, out);
}

// Round 14
// 125.801 us; speedup vs baseline: 1.0908x; 1.0198x over previous
//
#include <hip/hip_runtime.h>

// Medical2DSliceRenderer on MI355X (gfx950) — round 13 (resubmit; R12 bench
// window hit GPU-acquisition timeout, no data was collected)
//
//   mm = c0 x^2 + c1 xy + c2 y^2 + c3 x + c4 y + c5'
//   c5' = quad(mu) + log2(op*mask) + L,  L = 0.5*log2(ft/op), rr = 2^-L
//   h = exp2(mm);  S1 += h*rr (= g*op);  S2 += h*h (= g^2*op*ft)
//   img = sum_c [prod_{c'<c}(1-S1_c')] * S2_c
//
// Round 13 = R9 (best: 54.5us render, s_load feed, 8 rows/lane fold) with ONE
// change: the rr exponent-fold (validated in R11/R12) removes the g*g mul ->
// per-512-elem iteration 43 -> 35 VALU (-19% VALU issue). Feed scoreboard
// after R9-R12: s_load 39.5us busy-time < LDS 48.6 < readlane 55; occupancy
// proven irrelevant to the residual stall (R10). Minimal-delta A/B vs R9.

#define EPSV 1e-6f
#define NG   4096
#define PP   16384
#define NSL  4
#define NCS  32          // (chunk,seg): 4 chunks x 8 segments
#define GSEG 128         // gaussians per segment
#define SUBB 16          // gaussians per sub-block (8 per segment)

__global__ void prep_kernel(const float* __restrict__ means,
                            const float* __restrict__ scales,
                            const float* __restrict__ rots,
                            const float* __restrict__ ops,
                            const float* __restrict__ fts,
                            float4* __restrict__ gdata) {
    __shared__ float red[256];
    int tid = threadIdx.x;

    float m = -1e30f;
    for (int i = tid; i < NG; i += 256) m = fmaxf(m, scales[i*3+2]);
    red[tid] = m;
    __syncthreads();
    for (int s = 128; s > 0; s >>= 1) {
        if (tid < s) red[tid] = fmaxf(red[tid], red[tid+s]);
        __syncthreads();
    }
    float maxd = 3.0f * red[0];

    int g = blockIdx.x * 256 + tid;
    if (g >= NG) return;

    float qw = rots[g*4+0], qx = rots[g*4+1], qy = rots[g*4+2], qz = rots[g*4+3];
    float inorm = rsqrtf(qw*qw + qx*qx + qy*qy + qz*qz);
    qw *= inorm; qx *= inorm; qy *= inorm; qz *= inorm;

    float s0 = scales[g*3+0], s1 = scales[g*3+1], s2 = scales[g*3+2];

    float r00 = 1.f - 2.f*(qy*qy + qz*qz), r01 = 2.f*(qx*qy - qw*qz), r02 = 2.f*(qx*qz + qw*qy);
    float r10 = 2.f*(qx*qy + qw*qz), r11 = 1.f - 2.f*(qx*qx + qz*qz), r12 = 2.f*(qy*qz - qw*qx);
    float r20 = 2.f*(qx*qz - qw*qy), r21 = 2.f*(qy*qz + qw*qx), r22 = 1.f - 2.f*(qx*qx + qy*qy);

    float a00 = r00*s0, a01 = r01*s1, a02 = r02*s2;
    float a10 = r10*s0, a11 = r11*s1, a12 = r12*s2;
    float a20 = r20*s0, a21 = r21*s1, a22 = r22*s2;

    float c00 = a00*a00 + a01*a01 + a02*a02;
    float c01 = a00*a10 + a01*a11 + a02*a12;
    float c02 = a00*a20 + a01*a21 + a02*a22;
    float c11 = a10*a10 + a11*a11 + a12*a12;
    float c12 = a10*a20 + a11*a21 + a12*a22;
    float c22 = a20*a20 + a21*a21 + a22*a22;

    float izz = 1.0f / (c22 + EPSV);
    float kx = c02 * izz, ky = c12 * izz;
    float sa = c00 - c02*c02*izz + EPSV;
    float sb = c01 - c02*c12*izz;
    float sd = c11 - c12*c12*izz + EPSV;
    float det = sa*sd - sb*sb;
    float idet = 1.0f / det;

    const float C0 = -0.72134752044448170f;   // -0.5 * log2(e)
    float qa = C0 * sd * idet;            // x^2 coeff
    float qb = C0 * (-2.0f * sb * idet);  // xy coeff
    float qd = C0 * sa * idet;            // y^2 coeff

    float mx = means[g*3+0], my = means[g*3+1], mz = means[g*3+2];
    float op = ops[g], ft = fts[g];

    #pragma unroll
    for (int s = 0; s < NSL; ++s) {
        float z = -0.15f + 0.1f * (float)s;
        float zoff = z - mz;
        float m2x = mx + kx * zoff;
        float m2y = my + ky * zoff;
        bool live = (fabsf(mz - z) < maxd) && (op > 1e-12f);

        float c3 = -(2.0f*qa*m2x + qb*m2y);
        float c4 = -(2.0f*qd*m2y + qb*m2x);
        float c5q = qa*m2x*m2x + qb*m2x*m2y + qd*m2y*m2y;

        float c5p, rr;
        if (live) {
            float lop  = __log2f(op);
            float ftop = fmaxf(ft / op, 1e-20f);
            float L    = 0.5f * __log2f(ftop);
            c5p = c5q + lop + L;
            rr  = exp2f(-L);
        } else {
            c5p = -__builtin_inff();
            rr  = 0.f;
        }
        float4* o = gdata + ((size_t)s * NG + g) * 2;
        o[0] = make_float4(qa, qb, qd, c3);    // c0 c1 c2 c3
        o[1] = make_float4(c4, c5p, rr, 0.f);  // c4 c5' rr pad
    }
}

// R9 geometry: 512 blocks x 512 thr (8 waves). b: cs = b&31 (chunk*8+seg),
// band = b>>5 (slice, 32-row band). Wave w: ch = w&1 column half,
// rbase = (band&3)*32 + (w>>1)*8. All 8 waves stream the SAME 4KB segment
// (K$-resident) with rotated sub-block starts. s_load feed.
__global__ __launch_bounds__(512, 4)
void render_kernel(const float4* __restrict__ gdata, float2* __restrict__ part) {
    int tid   = threadIdx.x;
    int lane  = tid & 63;
    int w     = __builtin_amdgcn_readfirstlane(tid >> 6);   // 0..7
    int b     = blockIdx.x;
    int cs    = b & (NCS - 1);
    int band  = b >> 5;          // 0..15
    int slice = band >> 2;
    int ch    = w & 1;
    int rbase = (band & 3) * 32 + (w >> 1) * 8;

    const float DL = 2.0f / 127.0f;
    float x = -1.0f + (float)(ch * 64 + lane) * DL;   // per-lane column

    float yv[8];
    #pragma unroll
    for (int j = 0; j < 8; ++j) yv[j] = -1.0f + (float)(rbase + j) * DL;

    const float4* base = gdata + ((size_t)slice * NG + (size_t)cs * GSEG) * 2;

    float s1[8], s2[8];
    #pragma unroll
    for (int j = 0; j < 8; ++j) { s1[j] = 0.f; s2[j] = 0.f; }

    for (int kk = 0; kk < 8; ++kk) {
        int sb = (w + kk) & 7;                    // rotated sub-block start
        const float4* q = base + sb * SUBB * 2;   // wave-uniform address
        #pragma unroll 8
        for (int t = 0; t < SUBB; ++t) {
            float4 A = q[2*t+0];   // c0 c1 c2 c3   (s_load, K$-shared)
            float4 B = q[2*t+1];   // c4 c5' rr pad
            float A1 = fmaf(A.x, x, A.w);    // c0*x + c3
            float A2 = fmaf(A.y, x, B.x);    // c1*x + c4
            float A3 = fmaf(A1,  x, B.y);    // A1*x + c5'
            #pragma unroll
            for (int j = 0; j < 8; ++j) {
                float wj = fmaf(A.z, yv[j], A2);
                float mj = fmaf(wj, yv[j], A3);
                float h  = __builtin_amdgcn_exp2f(mj);
                s1[j] = fmaf(h, B.z, s1[j]);   // h * 2^-L = g*op
                s2[j] = fmaf(h, h,  s2[j]);    // h^2     = g^2*op*ft
            }
        }
    }

    // plane-major partials: part[cs][slice*PP + row*128 + col]  (coalesced)
    size_t ob = (size_t)cs * (NSL * PP) + (size_t)slice * PP
              + (size_t)rbase * 128 + ch * 64 + lane;
    #pragma unroll
    for (int j = 0; j < 8; ++j)
        part[ob + (size_t)j * 128] = make_float2(s1[j], s2[j]);
}

// one thread per pixel: sum 8 segments per chunk, then 4-step recursion
__global__ __launch_bounds__(256)
void combine_kernel(const float2* __restrict__ part, float* __restrict__ out) {
    int px = blockIdx.x * 256 + threadIdx.x;
    float img = 0.f, acc = 0.f;
    #pragma unroll
    for (int c = 0; c < 4; ++c) {
        float S1 = 0.f, S2 = 0.f;
        #pragma unroll
        for (int s = 0; s < 8; ++s) {
            float2 v = part[(size_t)(c*8 + s) * (NSL*PP) + px];
            S1 += v.x;  S2 += v.y;
        }
        float om = 1.0f - acc;
        img = fmaf(om, S2, img);
        acc = fmaf(om, S1, acc);
    }
    out[px] = img;
}

extern "C" void kernel_launch(void* const* d_in, const int* in_sizes, int n_in,
                              void* d_out, int out_size, void* d_ws, size_t ws_size,
                              hipStream_t stream) {
    const float* means  = (const float*)d_in[0];
    const float* scales = (const float*)d_in[1];
    const float* rots   = (const float*)d_in[2];
    const float* ops    = (const float*)d_in[3];
    const float* fts    = (const float*)d_in[4];
    float* out = (float*)d_out;

    float4* gdata = (float4*)d_ws;                               // 512 KB
    float2* part  = (float2*)((char*)d_ws + (size_t)NSL*NG*32);  // 16.8 MB

    prep_kernel<<<NG/256, 256, 0, stream>>>(means, scales, rots, ops, fts, gdata);
    render_kernel<<<NCS * 16, 512, 0, stream>>>(gdata, part);
    combine_kernel<<<NSL*PP/256, 256, 0, stream>>>(part, out);
}